// Round 1
// 713.683 us; speedup vs baseline: 1.0320x; 1.0320x over previous
//
#include <hip/hip_runtime.h>
#include <cstdint>

// Shapes (fixed): B=4, L=512, H=8, Dk=Dv=64, dm=512
#define NB 4
#define NL 512
#define NH 8
#define ND 64
#define NDM 512

typedef __attribute__((ext_vector_type(8))) short short8;   // 8 bf16 (4 VGPRs)
typedef __attribute__((ext_vector_type(4))) float f32x4;    // MFMA accumulator

__device__ __forceinline__ unsigned short f2bf(float f){
  union { float f; unsigned u; } v; v.f = f;
  unsigned r = (v.u + 0x7fffu + ((v.u >> 16) & 1u)) >> 16;
  return (unsigned short)r;
}

__device__ __forceinline__ short8 ld8(const unsigned short* p){
  return *(const short8*)p;
}

__device__ __forceinline__ f32x4 mfma16(short8 a, short8 b, f32x4 c){
  return __builtin_amdgcn_mfma_f32_16x16x32_bf16(a, b, c, 0, 0, 0);
}

__device__ __forceinline__ float gelu_tanh(float x){
  float u = 0.7978845608028654f * (x + 0.044715f * x * x * x);
  return 0.5f * x * (1.f + tanhf(u));
}

// ---- fused prep: convert q,k,v f32->bf16 AND transpose+convert 6 weights ----
// blocks 0..3071: qkv convert (float4 granularity)
// blocks 3072..3263: weight transpose, coalesced reads, full-line (64B) writes
__global__ __launch_bounds__(256) void k_prep(const float* __restrict__ q,
    const float* __restrict__ k, const float* __restrict__ v,
    unsigned short* __restrict__ xin,
    const float* __restrict__ wqs, const float* __restrict__ wks,
    const float* __restrict__ wvs, const float* __restrict__ wself,
    const float* __restrict__ wdd, const float* __restrict__ wfc,
    unsigned short* __restrict__ Wt){
  int blk = blockIdx.x;
  int t = threadIdx.x;
  if (blk < 3072){
    int i = blk * 256 + t;                       // 0..786431 (float4 units)
    int w = i >> 18, r = i & 262143;
    const float* src = (w == 0) ? q : (w == 1) ? k : v;
    float4 f = *(const float4*)(src + (size_t)r * 4);
    unsigned lo = (unsigned)f2bf(f.x) | ((unsigned)f2bf(f.y) << 16);
    unsigned hi = (unsigned)f2bf(f.z) | ((unsigned)f2bf(f.w) << 16);
    uint2 o; o.x = lo; o.y = hi;
    *(uint2*)(xin + (size_t)w * 1048576 + (size_t)r * 4) = o;
  } else {
    // 49152 threads: 6 weights x (512 n x 16 kgroups); thread -> 32 k's of one row
    int i = (blk - 3072) * 256 + t;              // 0..49151
    int w = i >> 13;                             // weight id (8192 threads each)
    int rr = i & 8191;
    int kg = rr >> 9;                            // 0..15
    int n  = rr & 511;                           // lanes consecutive -> coalesced reads
    int k0 = kg * 32;
    const float* src = (w == 0) ? wqs : (w == 1) ? wks : (w == 2) ? wvs :
                       (w == 3) ? wself : (w == 4) ? wdd : wfc;
    unsigned pk[16];
#pragma unroll
    for (int j = 0; j < 16; j++){
      float a = src[(size_t)(k0 + 2 * j) * 512 + n];
      float b = src[(size_t)(k0 + 2 * j + 1) * 512 + n];
      pk[j] = (unsigned)f2bf(a) | ((unsigned)f2bf(b) << 16);
    }
    uint4* o4 = (uint4*)(Wt + (size_t)w * 262144 + (size_t)n * 512 + k0);
    o4[0] = make_uint4(pk[0],  pk[1],  pk[2],  pk[3]);
    o4[1] = make_uint4(pk[4],  pk[5],  pk[6],  pk[7]);
    o4[2] = make_uint4(pk[8],  pk[9],  pk[10], pk[11]);
    o4[3] = make_uint4(pk[12], pk[13], pk[14], pk[15]);
  }
}

// ---- fused projection GEMMs: [2048,512]@[512,512] -> permuted bf16 ----
// mode 0: qs (scale 1/8) -> [B,H,L,D]; 1: kh -> [B,H,L,D]; 2: vhT -> [B,H,D,L]
__global__ __launch_bounds__(256) void k_proj(const unsigned short* __restrict__ xin,
    const unsigned short* __restrict__ Wt, unsigned short* __restrict__ qsb,
    unsigned short* __restrict__ khb, unsigned short* __restrict__ vhT){
  int wid0 = blockIdx.x * 4 + (threadIdx.x >> 6);   // 0..12287
  int mode = wid0 >> 10;                            // 0,1,2 (block-uniform)
  int wid = wid0 & 1023;
  int lane = threadIdx.x & 63;
  int tm = wid >> 5, tn = wid & 31;
  int r = lane & 15, q = lane >> 4;
  const unsigned short* X = xin + (size_t)mode * 1048576;
  const unsigned short* W = Wt + (size_t)mode * 262144;
  unsigned short* dst = (mode == 0) ? qsb : (mode == 1) ? khb : vhT;
  const unsigned short* A  = X + (size_t)(tm * 16 + r) * 512 + q * 8;
  const unsigned short* Bp = W + (size_t)(tn * 16 + r) * 512 + q * 8;
  f32x4 acc = {0.f, 0.f, 0.f, 0.f};
  for (int kk = 0; kk < 512; kk += 32) acc = mfma16(ld8(A + kk), ld8(Bp + kk), acc);
  int col = tn * 16 + r;
  int h = col >> 6, d = col & 63;
  float sc = (mode == 0) ? 0.125f : 1.0f;
  for (int i = 0; i < 4; i++){
    int row = tm * 16 + q * 4 + i;
    int b = row >> 9, l = row & 511;
    float vv = acc[i] * sc;
    size_t idx = (mode == 2) ? ((size_t)((b * 8 + h) * 64 + d) * 512 + l)
                             : ((size_t)((b * 8 + h) * 512 + l) * 64 + d);
    dst[idx] = f2bf(vv);
  }
}

// ---- content scores: per (b,h): qs[512,64] @ kh[512,64]^T -> f32 ----
// widened: each wave does 1 tm x 4 tn tiles (A fragment reuse)
__global__ __launch_bounds__(256) void k_scores(const unsigned short* __restrict__ qs,
    const unsigned short* __restrict__ kh, float* __restrict__ attnF){
  int wid = blockIdx.x * 4 + (threadIdx.x >> 6);    // 0..8191
  int lane = threadIdx.x & 63;
  int bh = wid >> 8;                                // 0..31
  int rest = wid & 255;
  int tm = rest >> 3, tg = rest & 7;
  int r = lane & 15, q = lane >> 4;
  const unsigned short* A = qs + (size_t)bh * 512 * 64 + (size_t)(tm * 16 + r) * 64 + q * 8;
  short8 a0 = ld8(A), a1 = ld8(A + 32);
  float* C = attnF + (size_t)bh * 512 * 512;
  for (int tn = tg * 4; tn < tg * 4 + 4; tn++){
    const unsigned short* Bp = kh + (size_t)bh * 512 * 64 + (size_t)(tn * 16 + r) * 64 + q * 8;
    f32x4 acc = {0.f, 0.f, 0.f, 0.f};
    acc = mfma16(a0, ld8(Bp),      acc);
    acc = mfma16(a1, ld8(Bp + 32), acc);
    for (int i = 0; i < 4; i++){
      int row = tm * 16 + q * 4 + i;
      C[(size_t)row * 512 + tn * 16 + r] = acc[i];
    }
  }
}

// ---- rel scores (stream vec_adj_k) + mask + softmax, per (b,l) ----
__global__ __launch_bounds__(256) void k_relsoft(const unsigned short* __restrict__ qs,
    const float* __restrict__ vak, const int* __restrict__ adj,
    float* __restrict__ attnF, unsigned short* __restrict__ attn_bf){
  int bid = blockIdx.x;
  int b = bid >> 9, l = bid & 511;
  int t = threadIdx.x, lane = t & 63, w = t >> 6;
  __shared__ __align__(16) unsigned short qsA[16 * 64];
  __shared__ __align__(16) unsigned short vkt[128 * 72];   // [m][d], stride 72
  __shared__ float sc[8 * 512];
  __shared__ int adjs[512];
  for (int j = 0; j < 4; j++){
    int e = t + j * 256;
    int m = e >> 6, d = e & 63;
    qsA[e] = (m < 8) ? qs[((size_t)((b * 8 + m) * 512 + l)) * 64 + d] : (unsigned short)0;
  }
  for (int j = 0; j < 16; j++){
    int e = t + j * 256;
    int h = e >> 9, m = e & 511;
    sc[e] = attnF[((size_t)(b * 8 + h) * 512 + l) * 512 + m];
  }
  adjs[t]       = adj[(size_t)bid * 512 + t];
  adjs[t + 256] = adj[(size_t)bid * 512 + t + 256];
  __syncthreads();
  int r = lane & 15, q = lane >> 4;
  short8 a0 = ld8(qsA + r * 64 + q * 8);
  short8 a1 = ld8(qsA + r * 64 + 32 + q * 8);
  const float* vrow = vak + (size_t)bid * 512 * 64;
  for (int c = 0; c < 4; c++){
    for (int it = 0; it < 8; it++){
      int i4 = it * 256 + t;                    // 2048 float4 per 128x64 chunk
      int m = i4 >> 4, d4 = (i4 & 15) * 4;
      const float4 f = *(const float4*)(vrow + (size_t)(c * 128 + m) * 64 + d4);
      unsigned p0 = (unsigned)f2bf(f.x) | ((unsigned)f2bf(f.y) << 16);
      unsigned p1 = (unsigned)f2bf(f.z) | ((unsigned)f2bf(f.w) << 16);
      uint2 pp; pp.x = p0; pp.y = p1;
      *(uint2*)(&vkt[m * 72 + d4]) = pp;
    }
    __syncthreads();
    for (int nt2 = 0; nt2 < 2; nt2++){
      int nt = w * 2 + nt2;
      const unsigned short* bp = vkt + (nt * 16 + r) * 72 + q * 8;
      f32x4 acc = {0.f, 0.f, 0.f, 0.f};
      acc = mfma16(a0, ld8(bp),      acc);
      acc = mfma16(a1, ld8(bp + 32), acc);
      if (q < 2){
        for (int i = 0; i < 4; i++){
          int h = q * 4 + i;                    // rows 0..7 = heads
          sc[h * 512 + c * 128 + nt * 16 + r] += acc[i];
        }
      }
    }
    __syncthreads();
  }
  // mask + softmax: wave w handles rows 2w, 2w+1
  for (int hh = 0; hh < 2; hh++){
    int h = w * 2 + hh;
    float v[8]; float mx = -3.0e38f;
    for (int i = 0; i < 8; i++){
      int m = lane + i * 64;
      float s = sc[h * 512 + m];
      if (adjs[m] == 0) s = -10000.0f;
      v[i] = s; mx = fmaxf(mx, s);
    }
    for (int off = 32; off; off >>= 1) mx = fmaxf(mx, __shfl_xor(mx, off, 64));
    float sum = 0.f;
    for (int i = 0; i < 8; i++){ v[i] = __expf(v[i] - mx); sum += v[i]; }
    for (int off = 32; off; off >>= 1) sum += __shfl_xor(sum, off, 64);
    float inv = 1.f / sum;
    size_t base = ((size_t)(b * 8 + h) * 512 + l) * 512;
    for (int i = 0; i < 8; i++){
      int m = lane + i * 64;
      float p2 = v[i] * inv;
      attnF[base + m] = p2;
      attn_bf[base + m] = f2bf(p2);
    }
  }
}

// ---- out content: per (b,h): attn[512,512] @ vh[512,64] -> qc f32 ----
__global__ __launch_bounds__(256) void k_outc(const unsigned short* __restrict__ attn_bf,
    const unsigned short* __restrict__ vhT, float* __restrict__ qc){
  int wid = blockIdx.x * 4 + (threadIdx.x >> 6);
  int lane = threadIdx.x & 63;
  int bh = wid >> 7, tile = wid & 127;
  int tm = tile >> 2, tn = tile & 3;
  int r = lane & 15, q = lane >> 4;
  const unsigned short* A  = attn_bf + (size_t)bh * 512 * 512 + (size_t)(tm * 16 + r) * 512 + q * 8;
  const unsigned short* Bp = vhT + (size_t)bh * 64 * 512 + (size_t)(tn * 16 + r) * 512 + q * 8;
  f32x4 acc = {0.f, 0.f, 0.f, 0.f};
  for (int k = 0; k < 512; k += 32) acc = mfma16(ld8(A + k), ld8(Bp + k), acc);
  int b = bh >> 3, h = bh & 7;
  int d = tn * 16 + r;
  for (int i = 0; i < 4; i++){
    int lrow = tm * 16 + q * 4 + i;
    qc[(size_t)(b * 512 + lrow) * 512 + h * 64 + d] = acc[i];
  }
}

// ---- out rel (stream vec_adj_v) + qc finalize + node_weight + denom ----
__global__ __launch_bounds__(256) void k_outrel(const unsigned short* __restrict__ attn_bf,
    const float* __restrict__ vav, const float* __restrict__ qc,
    const int* __restrict__ adj, const float* __restrict__ wnw,
    unsigned short* __restrict__ qc_bf, float* __restrict__ nw, float* __restrict__ invden){
  int bid = blockIdx.x;
  int b = bid >> 9, l = bid & 511;
  int t = threadIdx.x, lane = t & 63, w = t >> 6;
  __shared__ __align__(16) unsigned short vvT[64 * 136];   // [d][m], stride 136
  __shared__ float orL[512];
  __shared__ float redf[4];
  __shared__ int redi[4];
  int r = lane & 15, q = lane >> 4;
  int h8 = r & 7;
  const float* vrow = vav + (size_t)bid * 512 * 64;
  const unsigned short* arow = attn_bf + ((size_t)(b * 8 + h8) * 512 + l) * 512;
  f32x4 acc = {0.f, 0.f, 0.f, 0.f};
  for (int c = 0; c < 4; c++){
    for (int it = 0; it < 8; it++){
      int i4 = it * 256 + t;
      int m = i4 >> 4, d4 = (i4 & 15) * 4;
      const float4 f = *(const float4*)(vrow + (size_t)(c * 128 + m) * 64 + d4);
      vvT[(d4    ) * 136 + m] = f2bf(f.x);     // transposed store
      vvT[(d4 + 1) * 136 + m] = f2bf(f.y);
      vvT[(d4 + 2) * 136 + m] = f2bf(f.z);
      vvT[(d4 + 3) * 136 + m] = f2bf(f.w);
    }
    __syncthreads();
    for (int s = 0; s < 4; s++){
      int kk = c * 128 + s * 32;
      short8 av = ld8(arow + kk + q * 8);
      short8 bv = ld8(vvT + (w * 16 + r) * 136 + s * 32 + q * 8);
      acc = mfma16(av, bv, acc);
    }
    __syncthreads();
  }
  if (q < 2){
    for (int i = 0; i < 4; i++){
      int h = q * 4 + i;
      orL[h * 64 + w * 16 + r] = acc[i];
    }
  }
  __syncthreads();
  float part = 0.f; int asum = 0;
  for (int j = 0; j < 2; j++){
    int e = t + j * 256;
    float val = qc[(size_t)bid * 512 + e] + orL[e];
    qc_bf[(size_t)bid * 512 + e] = f2bf(val);
    part += val * wnw[e];
    asum += adj[(size_t)bid * 512 + e];
  }
  for (int off = 32; off; off >>= 1){
    part += __shfl_xor(part, off, 64);
    asum += __shfl_xor(asum, off, 64);
  }
  if (lane == 0){ redf[w] = part; redi[w] = asum; }
  __syncthreads();
  if (t == 0){
    float tot = redf[0] + redf[1] + redf[2] + redf[3];
    int at = redi[0] + redi[1] + redi[2] + redi[3];
    nw[bid] = 1.f / (1.f + __expf(-tot));
    invden[bid] = 1.f / ((at >= 1) ? (float)at : 1.f);
  }
}

// ---- fused post stage: selfi GEMM + ddT GEMM (LDS-transposed store) + ddw ----
// blocks 0..1023: selfi = qc@w_self (f32, coalesced)
// blocks 1024..2047: ddT = (qc@w_dd)^T bf16 via LDS transpose, ushort4 stores
// blocks 2048..6143: ddw[b,l,m] = adj ? nw[b,m]*invden[b,l] : 0 (bf16)
__global__ __launch_bounds__(256) void k_post(const unsigned short* __restrict__ qcb,
    const unsigned short* __restrict__ Wself, const unsigned short* __restrict__ Wdd,
    float* __restrict__ selfi, unsigned short* __restrict__ ddT,
    const int* __restrict__ adj, const float* __restrict__ nw,
    const float* __restrict__ invden, unsigned short* __restrict__ ddw){
  __shared__ __align__(16) unsigned short ldsT[64 * 20];   // stride 20 -> 8B aligned rows
  int blk = blockIdx.x;
  int t = threadIdx.x;
  if (blk < 2048){
    int mode = blk >> 10;                       // 0: selfi, 1: ddT (block-uniform)
    int wv = t >> 6;
    int wid = (blk & 1023) * 4 + wv;            // 0..4095
    int lane = t & 63;
    int tm = wid >> 5, tn = wid & 31;
    int r = lane & 15, q = lane >> 4;
    const unsigned short* W = mode ? Wdd : Wself;
    const unsigned short* A  = qcb + (size_t)(tm * 16 + r) * 512 + q * 8;
    const unsigned short* Bp = W + (size_t)(tn * 16 + r) * 512 + q * 8;
    f32x4 acc = {0.f, 0.f, 0.f, 0.f};
    for (int kk = 0; kk < 512; kk += 32) acc = mfma16(ld8(A + kk), ld8(Bp + kk), acc);
    int col = tn * 16 + r;
    if (mode == 0){
      for (int i = 0; i < 4; i++){
        int row = tm * 16 + q * 4 + i;
        selfi[(size_t)row * 512 + col] = acc[i];
      }
    } else {
      // all 4 waves share tm (block covers 16 m-rows x 64 n-cols)
      int nLocal = wv * 16 + r;                 // 0..63
      for (int i = 0; i < 4; i++) ldsT[nLocal * 20 + q * 4 + i] = f2bf(acc[i]);
      __syncthreads();
      int tmB = ((blk & 1023) * 4) >> 5;        // common tm
      int tnBase = ((blk & 1023) * 4) & 31;     // tn of wave 0 (multiple of 4)
      int n = t >> 2, part = t & 3;
      ushort4 val = *(const ushort4*)(&ldsT[n * 20 + part * 4]);
      int b = (tmB * 16) >> 9;
      int m0 = (tmB * 16) & 511;
      int nGlob = tnBase * 16 + n;
      *(ushort4*)(&ddT[((size_t)(b * 512 + nGlob)) * 512 + m0 + part * 4]) = val;
    }
  } else {
    int i = (blk - 2048) * 256 + t;             // 0..1048575
    int b = i >> 18, rest = i & 262143;
    int l = rest >> 9, m = rest & 511;
    int a = adj[i];
    float v = a ? nw[b * 512 + m] * invden[b * 512 + l] : 0.f;
    ddw[i] = f2bf(v);
  }
}

// ---- agg GEMM per b: ddw[512,512]@dd_info[512,512] + self -> xbf bf16 ----
__global__ __launch_bounds__(256) void k_agg(const unsigned short* __restrict__ ddw,
    const unsigned short* __restrict__ ddT, const float* __restrict__ selfi,
    unsigned short* __restrict__ xbf){
  int wid = blockIdx.x * 4 + (threadIdx.x >> 6);
  int lane = threadIdx.x & 63;
  int b = wid >> 10, tile = wid & 1023;
  int tm = tile >> 5, tn = tile & 31;
  int r = lane & 15, q = lane >> 4;
  const unsigned short* A  = ddw + (size_t)b * 262144 + (size_t)(tm * 16 + r) * 512 + q * 8;
  const unsigned short* Bp = ddT + (size_t)b * 262144 + (size_t)(tn * 16 + r) * 512 + q * 8;
  f32x4 acc = {0.f, 0.f, 0.f, 0.f};
  for (int k = 0; k < 512; k += 32) acc = mfma16(ld8(A + k), ld8(Bp + k), acc);
  int col = tn * 16 + r;
  for (int i = 0; i < 4; i++){
    int row = b * 512 + tm * 16 + q * 4 + i;
    float x = acc[i] + selfi[(size_t)row * 512 + col];
    xbf[(size_t)row * 512 + col] = f2bf(x);
  }
}

// ---- final: xbf@Wfc -> gelu -> + residual -> qo f32 ----
__global__ __launch_bounds__(256) void k_fc(const unsigned short* __restrict__ xbf,
    const unsigned short* __restrict__ W, const float* __restrict__ qin,
    float* __restrict__ qo){
  int wid = blockIdx.x * 4 + (threadIdx.x >> 6);
  int lane = threadIdx.x & 63;
  int tm = wid >> 5, tn = wid & 31;
  int r = lane & 15, q = lane >> 4;
  const unsigned short* A  = xbf + (size_t)(tm * 16 + r) * 512 + q * 8;
  const unsigned short* Bp = W + (size_t)(tn * 16 + r) * 512 + q * 8;
  f32x4 acc = {0.f, 0.f, 0.f, 0.f};
  for (int k = 0; k < 512; k += 32) acc = mfma16(ld8(A + k), ld8(Bp + k), acc);
  int col = tn * 16 + r;
  for (int i = 0; i < 4; i++){
    int row = tm * 16 + q * 4 + i;
    qo[(size_t)row * 512 + col] = qin[(size_t)row * 512 + col] + gelu_tanh(acc[i]);
  }
}

extern "C" void kernel_launch(void* const* d_in, const int* in_sizes, int n_in,
                              void* d_out, int out_size, void* d_ws, size_t ws_size,
                              hipStream_t stream){
  const float* q    = (const float*)d_in[0];
  const float* k    = (const float*)d_in[1];
  const float* v    = (const float*)d_in[2];
  const float* vak  = (const float*)d_in[3];
  const float* vav  = (const float*)d_in[4];
  const int*   adjk = (const int*)d_in[5];
  // d_in[6] = adj_v: unused by the reference
  const float* wqs  = (const float*)d_in[7];
  const float* wks  = (const float*)d_in[8];
  const float* wvs  = (const float*)d_in[9];
  const float* wfc  = (const float*)d_in[10];
  const float* wnw  = (const float*)d_in[11];
  const float* wself= (const float*)d_in[12];
  const float* wdd  = (const float*)d_in[13];

  float* qo    = (float*)d_out;               // [4,512,512]
  float* attnF = qo + 1048576;                // [4,8,512,512]

  char* p = (char*)d_ws;
  unsigned short* xin   = (unsigned short*)p; p += 6291456;   // q,k,v bf16
  unsigned short* Wt    = (unsigned short*)p; p += 3145728;   // 6 transposed weights bf16
  unsigned short* qsb   = (unsigned short*)p; p += 2097152;   // [B,H,L,D]
  unsigned short* khb   = (unsigned short*)p; p += 2097152;   // [B,H,L,D]
  unsigned short* vhT   = (unsigned short*)p; p += 2097152;   // [B,H,D,L]
  unsigned short* attnb = (unsigned short*)p; p += 16777216;  // [B,H,L,L] bf16
  float*          qc    = (float*)p;          p += 4194304;   // [2048,512]
  unsigned short* qcb   = (unsigned short*)p; p += 2097152;
  float*          nw    = (float*)p;          p += 8192;
  float*          invd  = (float*)p;          p += 8192;
  float*          selfi = (float*)p;          p += 4194304;
  unsigned short* ddT   = (unsigned short*)p; p += 2097152;   // [B, n, m] bf16
  unsigned short* ddw   = (unsigned short*)p; p += 2097152;   // [B, l, m] bf16
  unsigned short* xbf   = (unsigned short*)p; p += 2097152;

  k_prep<<<3264, 256, 0, stream>>>(q, k, v, xin, wqs, wks, wvs, wself, wdd, wfc, Wt);
  k_proj<<<3072, 256, 0, stream>>>(xin, Wt, qsb, khb, vhT);
  k_scores<<<2048, 256, 0, stream>>>(qsb, khb, attnF);
  k_relsoft<<<2048, 256, 0, stream>>>(qsb, vak, adjk, attnF, attnb);
  k_outc<<<1024, 256, 0, stream>>>(attnb, vhT, qc);
  k_outrel<<<2048, 256, 0, stream>>>(attnb, vav, qc, adjk, wnw, qcb, nw, invd);
  k_post<<<6144, 256, 0, stream>>>(qcb, Wt + 786432, Wt + 1048576, selfi, ddT,
                                   adjk, nw, invd, ddw);
  k_agg<<<1024, 256, 0, stream>>>(ddw, ddT, selfi, xbf);
  k_fc<<<1024, 256, 0, stream>>>(xbf, Wt + 1310720, q, qo);
}

// Round 2
// 708.602 us; speedup vs baseline: 1.0394x; 1.0072x over previous
//
#include <hip/hip_runtime.h>
#include <cstdint>

// Shapes (fixed): B=4, L=512, H=8, Dk=Dv=64, dm=512

typedef __attribute__((ext_vector_type(8))) short short8;   // 8 bf16 (4 VGPRs)
typedef __attribute__((ext_vector_type(4))) float f32x4;    // MFMA accumulator

__device__ __forceinline__ unsigned short f2bf(float f){
  union { float f; unsigned u; } v; v.f = f;
  unsigned r = (v.u + 0x7fffu + ((v.u >> 16) & 1u)) >> 16;
  return (unsigned short)r;
}

__device__ __forceinline__ short8 ld8(const unsigned short* p){
  return *(const short8*)p;
}

__device__ __forceinline__ f32x4 mfma16(short8 a, short8 b, f32x4 c){
  return __builtin_amdgcn_mfma_f32_16x16x32_bf16(a, b, c, 0, 0, 0);
}

__device__ __forceinline__ float gelu_tanh(float x){
  float u = 0.7978845608028654f * (x + 0.044715f * x * x * x);
  return 0.5f * x * (1.f + tanhf(u));
}

__device__ __forceinline__ short8 pack8(float4 f0, float4 f1){
  short8 s;
  s[0] = (short)f2bf(f0.x); s[1] = (short)f2bf(f0.y);
  s[2] = (short)f2bf(f0.z); s[3] = (short)f2bf(f0.w);
  s[4] = (short)f2bf(f1.x); s[5] = (short)f2bf(f1.y);
  s[6] = (short)f2bf(f1.z); s[7] = (short)f2bf(f1.w);
  return s;
}

// ---- 64x64-per-wave GEMM inner loop: 4x4 f32x4 accumulators, 16 indep MFMA chains
template<int LDA, int LDB, int KSTEPS>
__device__ __forceinline__ void gemm64(const unsigned short* __restrict__ A,
                                       const unsigned short* __restrict__ Bp,
                                       f32x4 acc[4][4]){
#pragma unroll 2
  for (int ks = 0; ks < KSTEPS; ks++){
    int kk = ks * 32;
    short8 a[4], b[4];
#pragma unroll
    for (int i = 0; i < 4; i++){
      a[i] = ld8(A + (size_t)i * 16 * LDA + kk);
      b[i] = ld8(Bp + (size_t)i * 16 * LDB + kk);
    }
#pragma unroll
    for (int i = 0; i < 4; i++)
#pragma unroll
      for (int j = 0; j < 4; j++)
        acc[i][j] = mfma16(a[i], b[j], acc[i][j]);
  }
}

// ---- fused prep: convert q,k,v f32->bf16 AND transpose+convert 6 weights ----
__global__ __launch_bounds__(256) void k_prep(const float* __restrict__ q,
    const float* __restrict__ k, const float* __restrict__ v,
    unsigned short* __restrict__ xin,
    const float* __restrict__ wqs, const float* __restrict__ wks,
    const float* __restrict__ wvs, const float* __restrict__ wself,
    const float* __restrict__ wdd, const float* __restrict__ wfc,
    unsigned short* __restrict__ Wt){
  int blk = blockIdx.x;
  int t = threadIdx.x;
  if (blk < 3072){
    int i = blk * 256 + t;                       // 0..786431 (float4 units)
    int w = i >> 18, r = i & 262143;
    const float* src = (w == 0) ? q : (w == 1) ? k : v;
    float4 f = *(const float4*)(src + (size_t)r * 4);
    unsigned lo = (unsigned)f2bf(f.x) | ((unsigned)f2bf(f.y) << 16);
    unsigned hi = (unsigned)f2bf(f.z) | ((unsigned)f2bf(f.w) << 16);
    uint2 o; o.x = lo; o.y = hi;
    *(uint2*)(xin + (size_t)w * 1048576 + (size_t)r * 4) = o;
  } else {
    int i = (blk - 3072) * 256 + t;              // 0..49151
    int w = i >> 13;                             // weight id
    int rr = i & 8191;
    int kg = rr >> 9;                            // 0..15
    int n  = rr & 511;                           // coalesced reads
    int k0 = kg * 32;
    const float* src = (w == 0) ? wqs : (w == 1) ? wks : (w == 2) ? wvs :
                       (w == 3) ? wself : (w == 4) ? wdd : wfc;
    unsigned pk[16];
#pragma unroll
    for (int j = 0; j < 16; j++){
      float a = src[(size_t)(k0 + 2 * j) * 512 + n];
      float b = src[(size_t)(k0 + 2 * j + 1) * 512 + n];
      pk[j] = (unsigned)f2bf(a) | ((unsigned)f2bf(b) << 16);
    }
    uint4* o4 = (uint4*)(Wt + (size_t)w * 262144 + (size_t)n * 512 + k0);
    o4[0] = make_uint4(pk[0],  pk[1],  pk[2],  pk[3]);
    o4[1] = make_uint4(pk[4],  pk[5],  pk[6],  pk[7]);
    o4[2] = make_uint4(pk[8],  pk[9],  pk[10], pk[11]);
    o4[3] = make_uint4(pk[12], pk[13], pk[14], pk[15]);
  }
}

// ---- fused projection GEMMs: 3x [2048,512]@[512,512], 64x64 per wave ----
__global__ __launch_bounds__(256) void k_proj(const unsigned short* __restrict__ xin,
    const unsigned short* __restrict__ Wt, unsigned short* __restrict__ qsb,
    unsigned short* __restrict__ khb, unsigned short* __restrict__ vhT){
  int wid = blockIdx.x * 4 + (threadIdx.x >> 6);    // 0..767
  int mode = wid >> 8;                              // 0,1,2
  int tile = wid & 255;
  int tm = tile >> 3, tn = tile & 7;                // 32 x 8 tiles of 64x64
  int lane = threadIdx.x & 63;
  int r = lane & 15, qq = lane >> 4;
  const unsigned short* X = xin + (size_t)mode * 1048576;
  const unsigned short* W = Wt + (size_t)mode * 262144;
  unsigned short* dst = (mode == 0) ? qsb : (mode == 1) ? khb : vhT;
  const unsigned short* A  = X + (size_t)(tm * 64 + r) * 512 + qq * 8;
  const unsigned short* Bp = W + (size_t)(tn * 64 + r) * 512 + qq * 8;
  f32x4 acc[4][4] = {};
  gemm64<512, 512, 16>(A, Bp, acc);
  float scv = (mode == 0) ? 0.125f : 1.0f;
  int h = tn;                                       // col>>6 == tn (64-aligned)
#pragma unroll
  for (int i = 0; i < 4; i++)
#pragma unroll
    for (int j = 0; j < 4; j++)
#pragma unroll
      for (int e = 0; e < 4; e++){
        int row = tm * 64 + i * 16 + qq * 4 + e;
        int d = j * 16 + r;
        int bb = row >> 9, l = row & 511;
        unsigned short val = f2bf(acc[i][j][e] * scv);
        size_t idx = (mode == 2) ? ((size_t)((bb * 8 + h) * 64 + d) * 512 + l)
                                 : ((size_t)((bb * 8 + h) * 512 + l) * 64 + d);
        dst[idx] = val;
      }
}

// ---- content scores: per (b,h): qs[512,64] @ kh[512,64]^T, 64x64 per wave ----
__global__ __launch_bounds__(256) void k_scores(const unsigned short* __restrict__ qs,
    const unsigned short* __restrict__ kh, float* __restrict__ attnF){
  int wid = blockIdx.x * 4 + (threadIdx.x >> 6);    // 0..2047
  int bh = wid >> 6;                                // 0..31
  int tile = wid & 63;
  int tm = tile >> 3, tn = tile & 7;
  int lane = threadIdx.x & 63;
  int r = lane & 15, qq = lane >> 4;
  const unsigned short* A  = qs + (size_t)bh * 32768 + (size_t)(tm * 64 + r) * 64 + qq * 8;
  const unsigned short* Bp = kh + (size_t)bh * 32768 + (size_t)(tn * 64 + r) * 64 + qq * 8;
  f32x4 acc[4][4] = {};
  gemm64<64, 64, 2>(A, Bp, acc);
  float* C = attnF + (size_t)bh * 262144;
#pragma unroll
  for (int i = 0; i < 4; i++)
#pragma unroll
    for (int j = 0; j < 4; j++)
#pragma unroll
      for (int e = 0; e < 4; e++){
        int row = tm * 64 + i * 16 + qq * 4 + e;
        int col = tn * 64 + j * 16 + r;
        C[(size_t)row * 512 + col] = acc[i][j][e];
      }
}

// ---- rel scores (direct-B global loads, no LDS transpose) + mask + softmax ----
__global__ __launch_bounds__(256) void k_relsoft(const unsigned short* __restrict__ qs,
    const float* __restrict__ vak, const int* __restrict__ adj,
    float* __restrict__ attnF, unsigned short* __restrict__ attn_bf){
  int bid = blockIdx.x;
  int b = bid >> 9, l = bid & 511;
  int t = threadIdx.x, lane = t & 63, w = t >> 6;
  __shared__ __align__(16) unsigned short qsA[16 * 64];
  __shared__ float sc[8 * 512];
  __shared__ int adjs[512];
  for (int j = 0; j < 4; j++){
    int e = t + j * 256;
    int m = e >> 6, d = e & 63;
    qsA[e] = (m < 8) ? qs[((size_t)((b * 8 + m) * 512 + l)) * 64 + d] : (unsigned short)0;
  }
  for (int j = 0; j < 16; j++){
    int e = t + j * 256;
    int h = e >> 9, m = e & 511;
    sc[e] = attnF[((size_t)(b * 8 + h) * 512 + l) * 512 + m];
  }
  adjs[t]       = adj[(size_t)bid * 512 + t];
  adjs[t + 256] = adj[(size_t)bid * 512 + t + 256];
  __syncthreads();
  int r = lane & 15, qq = lane >> 4;
  short8 a0 = ld8(qsA + r * 64 + qq * 8);
  short8 a1 = ld8(qsA + r * 64 + 32 + qq * 8);
  const float* vrow = vak + (size_t)bid * 32768;
#pragma unroll
  for (int c = 0; c < 4; c++){
#pragma unroll
    for (int nt2 = 0; nt2 < 2; nt2++){
      int nt = w * 2 + nt2;
      int m0 = c * 128 + nt * 16 + r;
      const float* p = vrow + (size_t)m0 * 64 + qq * 8;
      float4 f0 = *(const float4*)(p);
      float4 f1 = *(const float4*)(p + 4);
      float4 f2 = *(const float4*)(p + 32);
      float4 f3 = *(const float4*)(p + 36);
      f32x4 acc = {0.f, 0.f, 0.f, 0.f};
      acc = mfma16(a0, pack8(f0, f1), acc);
      acc = mfma16(a1, pack8(f2, f3), acc);
      if (qq < 2){
#pragma unroll
        for (int i = 0; i < 4; i++){
          int h = qq * 4 + i;
          sc[h * 512 + c * 128 + nt * 16 + r] += acc[i];
        }
      }
    }
  }
  __syncthreads();
  // mask + softmax: wave w handles rows 2w, 2w+1
  for (int hh = 0; hh < 2; hh++){
    int h = w * 2 + hh;
    float v[8]; float mx = -3.0e38f;
    for (int i = 0; i < 8; i++){
      int m = lane + i * 64;
      float s = sc[h * 512 + m];
      if (adjs[m] == 0) s = -10000.0f;
      v[i] = s; mx = fmaxf(mx, s);
    }
    for (int off = 32; off; off >>= 1) mx = fmaxf(mx, __shfl_xor(mx, off, 64));
    float sum = 0.f;
    for (int i = 0; i < 8; i++){ v[i] = __expf(v[i] - mx); sum += v[i]; }
    for (int off = 32; off; off >>= 1) sum += __shfl_xor(sum, off, 64);
    float inv = 1.f / sum;
    size_t base = ((size_t)(b * 8 + h) * 512 + l) * 512;
    for (int i = 0; i < 8; i++){
      int m = lane + i * 64;
      float p2 = v[i] * inv;
      attnF[base + m] = p2;
      attn_bf[base + m] = f2bf(p2);
    }
  }
}

// ---- out content: per (b,h): attn[512,512] @ vh[512,64], 64x64 per wave ----
__global__ __launch_bounds__(256) void k_outc(const unsigned short* __restrict__ attn_bf,
    const unsigned short* __restrict__ vhT, float* __restrict__ qc){
  int wid = blockIdx.x * 4 + (threadIdx.x >> 6);    // 0..255
  int bh = wid >> 3;                                // 0..31
  int tm = wid & 7;                                 // 8 row-tiles, single col-tile
  int lane = threadIdx.x & 63;
  int r = lane & 15, qq = lane >> 4;
  const unsigned short* A  = attn_bf + (size_t)bh * 262144 + (size_t)(tm * 64 + r) * 512 + qq * 8;
  const unsigned short* Bp = vhT + (size_t)bh * 32768 + (size_t)r * 512 + qq * 8;
  f32x4 acc[4][4] = {};
  gemm64<512, 512, 16>(A, Bp, acc);
  int b = bh >> 3, h = bh & 7;
#pragma unroll
  for (int i = 0; i < 4; i++)
#pragma unroll
    for (int j = 0; j < 4; j++)
#pragma unroll
      for (int e = 0; e < 4; e++){
        int lrow = tm * 64 + i * 16 + qq * 4 + e;
        int d = j * 16 + r;
        qc[(size_t)(b * 512 + lrow) * 512 + h * 64 + d] = acc[i][j][e];
      }
}

// ---- out rel (direct-B gather, no LDS transpose) + qc finalize + nw + denom ----
__global__ __launch_bounds__(256) void k_outrel(const unsigned short* __restrict__ attn_bf,
    const float* __restrict__ vav, const float* __restrict__ qc,
    const int* __restrict__ adj, const float* __restrict__ wnw,
    unsigned short* __restrict__ qc_bf, float* __restrict__ nw, float* __restrict__ invden){
  int bid = blockIdx.x;
  int b = bid >> 9, l = bid & 511;
  int t = threadIdx.x, lane = t & 63, w = t >> 6;
  __shared__ float orL[512];
  __shared__ float redf[4];
  __shared__ int redi[4];
  int r = lane & 15, qq = lane >> 4;
  int h8 = r & 7;
  const float* vrow = vav + (size_t)bid * 32768;
  const unsigned short* arow = attn_bf + ((size_t)(b * 8 + h8) * 512 + l) * 512;
  f32x4 acc = {0.f, 0.f, 0.f, 0.f};
  int dcol = w * 16 + r;
#pragma unroll
  for (int c = 0; c < 4; c++){
#pragma unroll
    for (int s = 0; s < 4; s++){
      int kk = c * 128 + s * 32;
      short8 av = ld8(arow + kk + qq * 8);
      float fv[8];
#pragma unroll
      for (int j = 0; j < 8; j++)
        fv[j] = vrow[(size_t)(kk + qq * 8 + j) * 64 + dcol];
      short8 bv;
#pragma unroll
      for (int j = 0; j < 8; j++) bv[j] = (short)f2bf(fv[j]);
      acc = mfma16(av, bv, acc);
    }
  }
  if (qq < 2){
#pragma unroll
    for (int i = 0; i < 4; i++){
      int h = qq * 4 + i;
      orL[h * 64 + dcol] = acc[i];
    }
  }
  __syncthreads();
  float part = 0.f; int asum = 0;
  for (int j = 0; j < 2; j++){
    int e = t + j * 256;
    float val = qc[(size_t)bid * 512 + e] + orL[e];
    qc_bf[(size_t)bid * 512 + e] = f2bf(val);
    part += val * wnw[e];
    asum += adj[(size_t)bid * 512 + e];
  }
  for (int off = 32; off; off >>= 1){
    part += __shfl_xor(part, off, 64);
    asum += __shfl_xor(asum, off, 64);
  }
  if (lane == 0){ redf[w] = part; redi[w] = asum; }
  __syncthreads();
  if (t == 0){
    float tot = redf[0] + redf[1] + redf[2] + redf[3];
    int at = redi[0] + redi[1] + redi[2] + redi[3];
    nw[bid] = 1.f / (1.f + __expf(-tot));
    invden[bid] = 1.f / ((at >= 1) ? (float)at : 1.f);
  }
}

// ---- fused post: selfi GEMM + ddT GEMM (transposed scatter) + ddw build ----
__global__ __launch_bounds__(256) void k_post(const unsigned short* __restrict__ qcb,
    const unsigned short* __restrict__ Wself, const unsigned short* __restrict__ Wdd,
    float* __restrict__ selfi, unsigned short* __restrict__ ddT,
    const int* __restrict__ adj, const float* __restrict__ nw,
    const float* __restrict__ invden, unsigned short* __restrict__ ddw){
  int blk = blockIdx.x;
  int t = threadIdx.x;
  if (blk < 128){
    int mode = blk >> 6;                          // 0: selfi, 1: ddT
    int wid = (blk & 63) * 4 + (t >> 6);          // 0..255
    int tm = wid >> 3, tn = wid & 7;
    int lane = t & 63;
    int r = lane & 15, qq = lane >> 4;
    const unsigned short* W = mode ? Wdd : Wself;
    const unsigned short* A  = qcb + (size_t)(tm * 64 + r) * 512 + qq * 8;
    const unsigned short* Bp = W + (size_t)(tn * 64 + r) * 512 + qq * 8;
    f32x4 acc[4][4] = {};
    gemm64<512, 512, 16>(A, Bp, acc);
#pragma unroll
    for (int i = 0; i < 4; i++)
#pragma unroll
      for (int j = 0; j < 4; j++)
#pragma unroll
        for (int e = 0; e < 4; e++){
          int row = tm * 64 + i * 16 + qq * 4 + e;
          int col = tn * 64 + j * 16 + r;
          if (mode == 0)
            selfi[(size_t)row * 512 + col] = acc[i][j][e];
          else {
            int bb = row >> 9, m = row & 511;
            ddT[((size_t)(bb * 512 + col)) * 512 + m] = f2bf(acc[i][j][e]);
          }
        }
  } else {
    int i8 = ((blk - 128) * 256 + t) * 8;         // 0..1048568 step 8
    int bb = i8 >> 18, rest = i8 & 262143;
    int l = rest >> 9, m0 = rest & 511;
    int4 a0 = *(const int4*)(adj + i8);
    int4 a1 = *(const int4*)(adj + i8 + 4);
    float id = invden[bb * 512 + l];
    const float* nwb = nw + bb * 512 + m0;
    short8 o;
    o[0] = a0.x ? (short)f2bf(nwb[0] * id) : (short)0;
    o[1] = a0.y ? (short)f2bf(nwb[1] * id) : (short)0;
    o[2] = a0.z ? (short)f2bf(nwb[2] * id) : (short)0;
    o[3] = a0.w ? (short)f2bf(nwb[3] * id) : (short)0;
    o[4] = a1.x ? (short)f2bf(nwb[4] * id) : (short)0;
    o[5] = a1.y ? (short)f2bf(nwb[5] * id) : (short)0;
    o[6] = a1.z ? (short)f2bf(nwb[6] * id) : (short)0;
    o[7] = a1.w ? (short)f2bf(nwb[7] * id) : (short)0;
    *(short8*)(ddw + i8) = o;
  }
}

// ---- agg GEMM per b: ddw[512,512]@ddT^T + selfi -> xbf, 64x64 per wave ----
__global__ __launch_bounds__(256) void k_agg(const unsigned short* __restrict__ ddw,
    const unsigned short* __restrict__ ddT, const float* __restrict__ selfi,
    unsigned short* __restrict__ xbf){
  int wid = blockIdx.x * 4 + (threadIdx.x >> 6);   // 0..255
  int b = wid >> 6;
  int tile = wid & 63;
  int tm = tile >> 3, tn = tile & 7;
  int lane = threadIdx.x & 63;
  int r = lane & 15, qq = lane >> 4;
  const unsigned short* A  = ddw + (size_t)b * 262144 + (size_t)(tm * 64 + r) * 512 + qq * 8;
  const unsigned short* Bp = ddT + (size_t)b * 262144 + (size_t)(tn * 64 + r) * 512 + qq * 8;
  f32x4 acc[4][4] = {};
  gemm64<512, 512, 16>(A, Bp, acc);
#pragma unroll
  for (int i = 0; i < 4; i++)
#pragma unroll
    for (int j = 0; j < 4; j++)
#pragma unroll
      for (int e = 0; e < 4; e++){
        int row = b * 512 + tm * 64 + i * 16 + qq * 4 + e;
        int col = tn * 64 + j * 16 + r;
        float x = acc[i][j][e] + selfi[(size_t)row * 512 + col];
        xbf[(size_t)row * 512 + col] = f2bf(x);
      }
}

// ---- final: xbf@Wfc -> gelu -> + residual -> qo f32, 64x64 per wave ----
__global__ __launch_bounds__(256) void k_fc(const unsigned short* __restrict__ xbf,
    const unsigned short* __restrict__ W, const float* __restrict__ qin,
    float* __restrict__ qo){
  int wid = blockIdx.x * 4 + (threadIdx.x >> 6);   // 0..255
  int tm = wid >> 3, tn = wid & 7;
  int lane = threadIdx.x & 63;
  int r = lane & 15, qq = lane >> 4;
  const unsigned short* A  = xbf + (size_t)(tm * 64 + r) * 512 + qq * 8;
  const unsigned short* Bp = W + (size_t)(tn * 64 + r) * 512 + qq * 8;
  f32x4 acc[4][4] = {};
  gemm64<512, 512, 16>(A, Bp, acc);
#pragma unroll
  for (int i = 0; i < 4; i++)
#pragma unroll
    for (int j = 0; j < 4; j++)
#pragma unroll
      for (int e = 0; e < 4; e++){
        int row = tm * 64 + i * 16 + qq * 4 + e;
        int col = tn * 64 + j * 16 + r;
        qo[(size_t)row * 512 + col] = qin[(size_t)row * 512 + col] + gelu_tanh(acc[i][j][e]);
      }
}

extern "C" void kernel_launch(void* const* d_in, const int* in_sizes, int n_in,
                              void* d_out, int out_size, void* d_ws, size_t ws_size,
                              hipStream_t stream){
  const float* q    = (const float*)d_in[0];
  const float* k    = (const float*)d_in[1];
  const float* v    = (const float*)d_in[2];
  const float* vak  = (const float*)d_in[3];
  const float* vav  = (const float*)d_in[4];
  const int*   adjk = (const int*)d_in[5];
  // d_in[6] = adj_v: unused by the reference
  const float* wqs  = (const float*)d_in[7];
  const float* wks  = (const float*)d_in[8];
  const float* wvs  = (const float*)d_in[9];
  const float* wfc  = (const float*)d_in[10];
  const float* wnw  = (const float*)d_in[11];
  const float* wself= (const float*)d_in[12];
  const float* wdd  = (const float*)d_in[13];

  float* qo    = (float*)d_out;               // [4,512,512]
  float* attnF = qo + 1048576;                // [4,8,512,512]

  char* p = (char*)d_ws;
  unsigned short* xin   = (unsigned short*)p; p += 6291456;   // q,k,v bf16
  unsigned short* Wt    = (unsigned short*)p; p += 3145728;   // 6 transposed weights bf16
  unsigned short* qsb   = (unsigned short*)p; p += 2097152;   // [B,H,L,D]
  unsigned short* khb   = (unsigned short*)p; p += 2097152;   // [B,H,L,D]
  unsigned short* vhT   = (unsigned short*)p; p += 2097152;   // [B,H,D,L]
  unsigned short* attnb = (unsigned short*)p; p += 16777216;  // [B,H,L,L] bf16
  float*          qc    = (float*)p;          p += 4194304;   // [2048,512]
  unsigned short* qcb   = (unsigned short*)p; p += 2097152;
  float*          nw    = (float*)p;          p += 8192;
  float*          invd  = (float*)p;          p += 8192;
  float*          selfi = (float*)p;          p += 4194304;
  unsigned short* ddT   = (unsigned short*)p; p += 2097152;   // [B, n, m] bf16
  unsigned short* ddw   = (unsigned short*)p; p += 2097152;   // [B, l, m] bf16
  unsigned short* xbf   = (unsigned short*)p; p += 2097152;

  k_prep<<<3264, 256, 0, stream>>>(q, k, v, xin, wqs, wks, wvs, wself, wdd, wfc, Wt);
  k_proj<<<192, 256, 0, stream>>>(xin, Wt, qsb, khb, vhT);
  k_scores<<<512, 256, 0, stream>>>(qsb, khb, attnF);
  k_relsoft<<<2048, 256, 0, stream>>>(qsb, vak, adjk, attnF, attnb);
  k_outc<<<64, 256, 0, stream>>>(attnb, vhT, qc);
  k_outrel<<<2048, 256, 0, stream>>>(attnb, vav, qc, adjk, wnw, qcb, nw, invd);
  k_post<<<640, 256, 0, stream>>>(qcb, Wt + 786432, Wt + 1048576, selfi, ddT,
                                  adjk, nw, invd, ddw);
  k_agg<<<64, 256, 0, stream>>>(ddw, ddT, selfi, xbf);
  k_fc<<<64, 256, 0, stream>>>(xbf, Wt + 1310720, q, qo);
}

// Round 3
// 618.909 us; speedup vs baseline: 1.1900x; 1.1449x over previous
//
#include <hip/hip_runtime.h>
#include <cstdint>

// Shapes (fixed): B=4, L=512, H=8, Dk=Dv=64, dm=512

typedef __attribute__((ext_vector_type(8))) short short8;   // 8 bf16 (4 VGPRs)
typedef __attribute__((ext_vector_type(4))) float f32x4;    // MFMA accumulator

__device__ __forceinline__ unsigned short f2bf(float f){
  union { float f; unsigned u; } v; v.f = f;
  unsigned r = (v.u + 0x7fffu + ((v.u >> 16) & 1u)) >> 16;
  return (unsigned short)r;
}

__device__ __forceinline__ short8 ld8(const unsigned short* p){
  return *(const short8*)p;
}

__device__ __forceinline__ f32x4 mfma16(short8 a, short8 b, f32x4 c){
  return __builtin_amdgcn_mfma_f32_16x16x32_bf16(a, b, c, 0, 0, 0);
}

__device__ __forceinline__ float gelu_tanh(float x){
  float u = 0.7978845608028654f * (x + 0.044715f * x * x * x);
  return 0.5f * x * (1.f + tanhf(u));
}

__device__ __forceinline__ short8 pack8(float4 f0, float4 f1){
  short8 s;
  s[0] = (short)f2bf(f0.x); s[1] = (short)f2bf(f0.y);
  s[2] = (short)f2bf(f0.z); s[3] = (short)f2bf(f0.w);
  s[4] = (short)f2bf(f1.x); s[5] = (short)f2bf(f1.y);
  s[6] = (short)f2bf(f1.z); s[7] = (short)f2bf(f1.w);
  return s;
}

// ---- MTx64-per-wave GEMM inner loop (MT*4 independent MFMA chains) ----
template<int MT, int LDA, int LDB, int KSTEPS>
__device__ __forceinline__ void gemmT(const unsigned short* __restrict__ A,
                                      const unsigned short* __restrict__ Bp,
                                      f32x4 acc[MT][4]){
#pragma unroll 2
  for (int ks = 0; ks < KSTEPS; ks++){
    int kk = ks * 32;
    short8 a[MT], b[4];
#pragma unroll
    for (int i = 0; i < MT; i++) a[i] = ld8(A + (size_t)i * 16 * LDA + kk);
#pragma unroll
    for (int j = 0; j < 4; j++)  b[j] = ld8(Bp + (size_t)j * 16 * LDB + kk);
#pragma unroll
    for (int i = 0; i < MT; i++)
#pragma unroll
      for (int j = 0; j < 4; j++)
        acc[i][j] = mfma16(a[i], b[j], acc[i][j]);
  }
}

// ---- fused prep: convert q,k,v f32->bf16 AND transpose+convert 6 weights ----
__global__ __launch_bounds__(256) void k_prep(const float* __restrict__ q,
    const float* __restrict__ k, const float* __restrict__ v,
    unsigned short* __restrict__ xin,
    const float* __restrict__ wqs, const float* __restrict__ wks,
    const float* __restrict__ wvs, const float* __restrict__ wself,
    const float* __restrict__ wdd, const float* __restrict__ wfc,
    unsigned short* __restrict__ Wt){
  int blk = blockIdx.x;
  int t = threadIdx.x;
  if (blk < 3072){
    int i = blk * 256 + t;                       // float4 units
    int w = i >> 18, r = i & 262143;
    const float* src = (w == 0) ? q : (w == 1) ? k : v;
    float4 f = *(const float4*)(src + (size_t)r * 4);
    unsigned lo = (unsigned)f2bf(f.x) | ((unsigned)f2bf(f.y) << 16);
    unsigned hi = (unsigned)f2bf(f.z) | ((unsigned)f2bf(f.w) << 16);
    uint2 o; o.x = lo; o.y = hi;
    *(uint2*)(xin + (size_t)w * 1048576 + (size_t)r * 4) = o;
  } else {
    int i = (blk - 3072) * 256 + t;              // 0..49151
    int w = i >> 13;
    int rr = i & 8191;
    int kg = rr >> 9;
    int n  = rr & 511;
    int k0 = kg * 32;
    const float* src = (w == 0) ? wqs : (w == 1) ? wks : (w == 2) ? wvs :
                       (w == 3) ? wself : (w == 4) ? wdd : wfc;
    unsigned pk[16];
#pragma unroll
    for (int j = 0; j < 16; j++){
      float a = src[(size_t)(k0 + 2 * j) * 512 + n];
      float b = src[(size_t)(k0 + 2 * j + 1) * 512 + n];
      pk[j] = (unsigned)f2bf(a) | ((unsigned)f2bf(b) << 16);
    }
    uint4* o4 = (uint4*)(Wt + (size_t)w * 262144 + (size_t)n * 512 + k0);
    o4[0] = make_uint4(pk[0],  pk[1],  pk[2],  pk[3]);
    o4[1] = make_uint4(pk[4],  pk[5],  pk[6],  pk[7]);
    o4[2] = make_uint4(pk[8],  pk[9],  pk[10], pk[11]);
    o4[3] = make_uint4(pk[12], pk[13], pk[14], pk[15]);
  }
}

// ---- fused projection GEMMs: 3x [2048,512]@[512,512], 32x64 per wave ----
__global__ __launch_bounds__(256) void k_proj(const unsigned short* __restrict__ xin,
    const unsigned short* __restrict__ Wt, unsigned short* __restrict__ qsb,
    unsigned short* __restrict__ khb, unsigned short* __restrict__ vhT){
  int wid = blockIdx.x * 4 + (threadIdx.x >> 6);    // 0..1535
  int mode = wid >> 9;                              // 0,1,2
  int tile = wid & 511;
  int tm = tile >> 3, tn = tile & 7;
  int lane = threadIdx.x & 63;
  int r = lane & 15, qq = lane >> 4;
  const unsigned short* X = xin + (size_t)mode * 1048576;
  const unsigned short* W = Wt + (size_t)mode * 262144;
  unsigned short* dst = (mode == 0) ? qsb : (mode == 1) ? khb : vhT;
  const unsigned short* A  = X + (size_t)(tm * 32 + r) * 512 + qq * 8;
  const unsigned short* Bp = W + (size_t)(tn * 64 + r) * 512 + qq * 8;
  f32x4 acc[2][4] = {};
  gemmT<2, 512, 512, 16>(A, Bp, acc);
  float scv = (mode == 0) ? 0.125f : 1.0f;
  int h = tn;
#pragma unroll
  for (int i = 0; i < 2; i++)
#pragma unroll
    for (int j = 0; j < 4; j++)
#pragma unroll
      for (int e = 0; e < 4; e++){
        int row = tm * 32 + i * 16 + qq * 4 + e;
        int d = j * 16 + r;
        int bb = row >> 9, l = row & 511;
        unsigned short val = f2bf(acc[i][j][e] * scv);
        size_t idx = (mode == 2) ? ((size_t)((bb * 8 + h) * 64 + d) * 512 + l)
                                 : ((size_t)((bb * 8 + h) * 512 + l) * 64 + d);
        dst[idx] = val;
      }
}

// ---- content scores: per (b,h): qs[512,64] @ kh[512,64]^T, 64x64 per wave ----
__global__ __launch_bounds__(256) void k_scores(const unsigned short* __restrict__ qs,
    const unsigned short* __restrict__ kh, float* __restrict__ attnF){
  int wid = blockIdx.x * 4 + (threadIdx.x >> 6);    // 0..2047
  int bh = wid >> 6;
  int tile = wid & 63;
  int tm = tile >> 3, tn = tile & 7;
  int lane = threadIdx.x & 63;
  int r = lane & 15, qq = lane >> 4;
  const unsigned short* A  = qs + (size_t)bh * 32768 + (size_t)(tm * 64 + r) * 64 + qq * 8;
  const unsigned short* Bp = kh + (size_t)bh * 32768 + (size_t)(tn * 64 + r) * 64 + qq * 8;
  f32x4 acc[4][4] = {};
  gemmT<4, 64, 64, 2>(A, Bp, acc);
  float* C = attnF + (size_t)bh * 262144;
#pragma unroll
  for (int i = 0; i < 4; i++)
#pragma unroll
    for (int j = 0; j < 4; j++)
#pragma unroll
      for (int e = 0; e < 4; e++){
        int row = tm * 64 + i * 16 + qq * 4 + e;
        int col = tn * 64 + j * 16 + r;
        C[(size_t)row * 512 + col] = acc[i][j][e];
      }
}

// ---- rel scores: gather UNMASKED m only (attn at masked m is exactly 0) ----
__global__ __launch_bounds__(256) void k_relsoft(const unsigned short* __restrict__ qs,
    const float* __restrict__ vak, const int* __restrict__ adj,
    float* __restrict__ attnF, unsigned short* __restrict__ attn_bf){
  int bid = blockIdx.x;
  int b = bid >> 9, l = bid & 511;
  int t = threadIdx.x, lane = t & 63, w = t >> 6;
  __shared__ __align__(16) unsigned short qsA[16 * 64];
  __shared__ float sc[8 * 512];
  __shared__ short Mlist[512];
  __shared__ int lds4[4];
  for (int j = 0; j < 4; j++){
    int e = t + j * 256;
    int m = e >> 6, d = e & 63;
    qsA[e] = (m < 8) ? qs[((size_t)((b * 8 + m) * 512 + l)) * 64 + d] : (unsigned short)0;
  }
  // mask values for this thread's sc-init positions (m = t and t+256)
  int am0 = adj[(size_t)bid * 512 + t];
  int am1 = adj[(size_t)bid * 512 + t + 256];
  for (int j = 0; j < 16; j++){
    int e = t + j * 256;
    int h = e >> 9, m = e & 511;
    float s = attnF[((size_t)(b * 8 + h) * 512 + l) * 512 + m];
    int msk = (j & 1) ? am1 : am0;
    sc[e] = msk ? s : -10000.0f;                 // pre-apply mask
  }
  // prefix-scan adj -> compacted index list (increasing m)
  int2 av2 = *(const int2*)(adj + (size_t)bid * 512 + 2 * t);
  int c = av2.x + av2.y;
  int incl = c;
  for (int off = 1; off < 64; off <<= 1){
    int n = __shfl_up(incl, off, 64);
    if (lane >= off) incl += n;
  }
  if (lane == 63) lds4[w] = incl;
  __syncthreads();
  int base = 0;
  for (int i = 0; i < w; i++) base += lds4[i];
  int cnt = lds4[0] + lds4[1] + lds4[2] + lds4[3];
  int excl = base + incl - c;
  if (av2.x){ Mlist[excl] = (short)(2 * t); excl++; }
  if (av2.y){ Mlist[excl] = (short)(2 * t + 1); }
  int padded = (cnt + 31) & ~31;
  for (int i2 = cnt + t; i2 < padded; i2 += 256) Mlist[i2] = 0;
  __syncthreads();
  int r = lane & 15, qq = lane >> 4;
  short8 a0 = ld8(qsA + r * 64 + qq * 8);
  short8 a1 = ld8(qsA + r * 64 + 32 + qq * 8);
  const float* vrow = vak + (size_t)bid * 32768;
  int ntiles = (cnt + 15) >> 4;
  for (int tile = w; tile < ntiles; tile += 4){
    int gi = tile * 16 + r;
    int m = Mlist[gi];
    const float* p = vrow + (size_t)m * 64 + qq * 8;
    float4 f0 = *(const float4*)(p);
    float4 f1 = *(const float4*)(p + 4);
    float4 f2 = *(const float4*)(p + 32);
    float4 f3 = *(const float4*)(p + 36);
    f32x4 acc = {0.f, 0.f, 0.f, 0.f};
    acc = mfma16(a0, pack8(f0, f1), acc);
    acc = mfma16(a1, pack8(f2, f3), acc);
    if (qq < 2){
#pragma unroll
      for (int i = 0; i < 4; i++){
        int h = qq * 4 + i;
        if (gi < cnt) sc[h * 512 + m] += acc[i];
      }
    }
  }
  __syncthreads();
  // softmax: wave w handles rows 2w, 2w+1 (mask already applied in sc)
  for (int hh = 0; hh < 2; hh++){
    int h = w * 2 + hh;
    float v[8]; float mx = -3.0e38f;
    for (int i = 0; i < 8; i++){
      int m = lane + i * 64;
      v[i] = sc[h * 512 + m]; mx = fmaxf(mx, v[i]);
    }
    for (int off = 32; off; off >>= 1) mx = fmaxf(mx, __shfl_xor(mx, off, 64));
    float sum = 0.f;
    for (int i = 0; i < 8; i++){ v[i] = __expf(v[i] - mx); sum += v[i]; }
    for (int off = 32; off; off >>= 1) sum += __shfl_xor(sum, off, 64);
    float inv = 1.f / sum;
    size_t base2 = ((size_t)(b * 8 + h) * 512 + l) * 512;
    for (int i = 0; i < 8; i++){
      int m = lane + i * 64;
      float p2 = v[i] * inv;
      attnF[base2 + m] = p2;
      attn_bf[base2 + m] = f2bf(p2);
    }
  }
}

// ---- out content: per (b,h): attn[512,512] @ vh[512,64], 32x64 per wave ----
__global__ __launch_bounds__(256) void k_outc(const unsigned short* __restrict__ attn_bf,
    const unsigned short* __restrict__ vhT, float* __restrict__ qc){
  int wid = blockIdx.x * 4 + (threadIdx.x >> 6);    // 0..511
  int bh = wid >> 4;
  int tm = wid & 15;
  int lane = threadIdx.x & 63;
  int r = lane & 15, qq = lane >> 4;
  const unsigned short* A  = attn_bf + (size_t)bh * 262144 + (size_t)(tm * 32 + r) * 512 + qq * 8;
  const unsigned short* Bp = vhT + (size_t)bh * 32768 + (size_t)r * 512 + qq * 8;
  f32x4 acc[2][4] = {};
  gemmT<2, 512, 512, 16>(A, Bp, acc);
  int b = bh >> 3, h = bh & 7;
#pragma unroll
  for (int i = 0; i < 2; i++)
#pragma unroll
    for (int j = 0; j < 4; j++)
#pragma unroll
      for (int e = 0; e < 4; e++){
        int lrow = tm * 32 + i * 16 + qq * 4 + e;
        int d = j * 16 + r;
        qc[(size_t)(b * 512 + lrow) * 512 + h * 64 + d] = acc[i][j][e];
      }
}

// ---- out rel: gather UNMASKED m only (attn exactly 0 at masked m) ----
__global__ __launch_bounds__(256) void k_outrel(const unsigned short* __restrict__ attn_bf,
    const float* __restrict__ vav, const float* __restrict__ qc,
    const int* __restrict__ adj, const float* __restrict__ wnw,
    unsigned short* __restrict__ qc_bf, float* __restrict__ nw, float* __restrict__ invden){
  int bid = blockIdx.x;
  int b = bid >> 9, l = bid & 511;
  int t = threadIdx.x, lane = t & 63, w = t >> 6;
  __shared__ __align__(16) unsigned short attnL[8][512];
  __shared__ __align__(16) unsigned short pAg[8][528];
  __shared__ short Mlist[512];
  __shared__ float orL[512];
  __shared__ float redf[4];
  __shared__ int lds4[4];
  int r = lane & 15, qq = lane >> 4;
  int h8 = r & 7;
  // stage attn rows (8 heads) coalesced
#pragma unroll
  for (int h = 0; h < 8; h++){
    const unsigned short* rowp = attn_bf + (((size_t)(b * 8 + h) * 512 + l) * 512);
    *(ushort2*)(&attnL[h][2 * t]) = *(const ushort2*)(rowp + 2 * t);
  }
  // prefix-scan adj -> compacted index list
  int2 av2 = *(const int2*)(adj + (size_t)bid * 512 + 2 * t);
  int c = av2.x + av2.y;
  int incl = c;
  for (int off = 1; off < 64; off <<= 1){
    int n = __shfl_up(incl, off, 64);
    if (lane >= off) incl += n;
  }
  if (lane == 63) lds4[w] = incl;
  __syncthreads();
  int base = 0;
  for (int i = 0; i < w; i++) base += lds4[i];
  int cnt = lds4[0] + lds4[1] + lds4[2] + lds4[3];
  int excl = base + incl - c;
  if (av2.x){ Mlist[excl] = (short)(2 * t); excl++; }
  if (av2.y){ Mlist[excl] = (short)(2 * t + 1); }
  int cntV = cnt;
  int padded0 = (cnt + 31) & ~31;
  for (int i2 = cnt + t; i2 < padded0; i2 += 256) Mlist[i2] = 0;
  __syncthreads();
  if (cnt == 0){                                   // all-masked row: uniform attn
    for (int i2 = t; i2 < 512; i2 += 256) Mlist[i2] = (short)i2;
    cntV = 512;
    __syncthreads();                               // uniform condition -> legal
  }
  int padded = (cntV + 31) & ~31;
  // build packed attn-gather operand (pads = 0)
  for (int j = t; j < padded; j += 256){
    int m = Mlist[j];
    bool vld = (j < cntV);
#pragma unroll
    for (int h = 0; h < 8; h++)
      pAg[h][j] = vld ? attnL[h][m] : (unsigned short)0;
  }
  __syncthreads();
  const float* vrow = vav + (size_t)bid * 32768;
  int dcol = w * 16 + r;
  f32x4 acc = {0.f, 0.f, 0.f, 0.f};
  int nks = padded >> 5;
  for (int s = 0; s < nks; s++){
    short8 av = ld8(&pAg[h8][s * 32 + qq * 8]);
    int mrow[8];
#pragma unroll
    for (int j = 0; j < 8; j++) mrow[j] = Mlist[s * 32 + qq * 8 + j];
    float fv[8];
#pragma unroll
    for (int j = 0; j < 8; j++) fv[j] = vrow[(size_t)mrow[j] * 64 + dcol];
    short8 bv;
#pragma unroll
    for (int j = 0; j < 8; j++) bv[j] = (short)f2bf(fv[j]);
    acc = mfma16(av, bv, acc);
  }
  if (qq < 2){
#pragma unroll
    for (int i = 0; i < 4; i++){
      int h = qq * 4 + i;
      orL[h * 64 + dcol] = acc[i];
    }
  }
  __syncthreads();
  float part = 0.f;
  for (int j = 0; j < 2; j++){
    int e = t + j * 256;
    float val = qc[(size_t)bid * 512 + e] + orL[e];
    qc_bf[(size_t)bid * 512 + e] = f2bf(val);
    part += val * wnw[e];
  }
  for (int off = 32; off; off >>= 1) part += __shfl_xor(part, off, 64);
  if (lane == 0) redf[w] = part;
  __syncthreads();
  if (t == 0){
    float tot = redf[0] + redf[1] + redf[2] + redf[3];
    nw[bid] = 1.f / (1.f + __expf(-tot));
    invden[bid] = 1.f / ((cnt >= 1) ? (float)cnt : 1.f);
  }
}

// ---- fused post: selfi GEMM + ddT GEMM (transposed scatter) + ddw build ----
__global__ __launch_bounds__(256) void k_post(const unsigned short* __restrict__ qcb,
    const unsigned short* __restrict__ Wself, const unsigned short* __restrict__ Wdd,
    float* __restrict__ selfi, unsigned short* __restrict__ ddT,
    const int* __restrict__ adj, const float* __restrict__ nw,
    const float* __restrict__ invden, unsigned short* __restrict__ ddw){
  int blk = blockIdx.x;
  int t = threadIdx.x;
  if (blk < 256){
    int mode = blk >> 7;                          // 0: selfi, 1: ddT
    int wid = (blk & 127) * 4 + (t >> 6);         // 0..511
    int tm = wid >> 3, tn = wid & 7;
    int lane = t & 63;
    int r = lane & 15, qq = lane >> 4;
    const unsigned short* W = mode ? Wdd : Wself;
    const unsigned short* A  = qcb + (size_t)(tm * 32 + r) * 512 + qq * 8;
    const unsigned short* Bp = W + (size_t)(tn * 64 + r) * 512 + qq * 8;
    f32x4 acc[2][4] = {};
    gemmT<2, 512, 512, 16>(A, Bp, acc);
#pragma unroll
    for (int i = 0; i < 2; i++)
#pragma unroll
      for (int j = 0; j < 4; j++)
#pragma unroll
        for (int e = 0; e < 4; e++){
          int row = tm * 32 + i * 16 + qq * 4 + e;
          int col = tn * 64 + j * 16 + r;
          if (mode == 0)
            selfi[(size_t)row * 512 + col] = acc[i][j][e];
          else {
            int bb = row >> 9, m = row & 511;
            ddT[((size_t)(bb * 512 + col)) * 512 + m] = f2bf(acc[i][j][e]);
          }
        }
  } else {
    int i8 = ((blk - 256) * 256 + t) * 8;
    int bb = i8 >> 18, rest = i8 & 262143;
    int l = rest >> 9, m0 = rest & 511;
    int4 a0 = *(const int4*)(adj + i8);
    int4 a1 = *(const int4*)(adj + i8 + 4);
    float id = invden[bb * 512 + l];
    const float* nwb = nw + bb * 512 + m0;
    short8 o;
    o[0] = a0.x ? (short)f2bf(nwb[0] * id) : (short)0;
    o[1] = a0.y ? (short)f2bf(nwb[1] * id) : (short)0;
    o[2] = a0.z ? (short)f2bf(nwb[2] * id) : (short)0;
    o[3] = a0.w ? (short)f2bf(nwb[3] * id) : (short)0;
    o[4] = a1.x ? (short)f2bf(nwb[4] * id) : (short)0;
    o[5] = a1.y ? (short)f2bf(nwb[5] * id) : (short)0;
    o[6] = a1.z ? (short)f2bf(nwb[6] * id) : (short)0;
    o[7] = a1.w ? (short)f2bf(nwb[7] * id) : (short)0;
    *(short8*)(ddw + i8) = o;
  }
}

// ---- agg GEMM per b: ddw[512,512]@ddT^T + selfi -> xbf, 32x64 per wave ----
__global__ __launch_bounds__(256) void k_agg(const unsigned short* __restrict__ ddw,
    const unsigned short* __restrict__ ddT, const float* __restrict__ selfi,
    unsigned short* __restrict__ xbf){
  int wid = blockIdx.x * 4 + (threadIdx.x >> 6);   // 0..511
  int b = wid >> 7;
  int tile = wid & 127;
  int tm = tile >> 3, tn = tile & 7;
  int lane = threadIdx.x & 63;
  int r = lane & 15, qq = lane >> 4;
  const unsigned short* A  = ddw + (size_t)b * 262144 + (size_t)(tm * 32 + r) * 512 + qq * 8;
  const unsigned short* Bp = ddT + (size_t)b * 262144 + (size_t)(tn * 64 + r) * 512 + qq * 8;
  f32x4 acc[2][4] = {};
  gemmT<2, 512, 512, 16>(A, Bp, acc);
#pragma unroll
  for (int i = 0; i < 2; i++)
#pragma unroll
    for (int j = 0; j < 4; j++)
#pragma unroll
      for (int e = 0; e < 4; e++){
        int row = b * 512 + tm * 32 + i * 16 + qq * 4 + e;
        int col = tn * 64 + j * 16 + r;
        float x = acc[i][j][e] + selfi[(size_t)row * 512 + col];
        xbf[(size_t)row * 512 + col] = f2bf(x);
      }
}

// ---- final: xbf@Wfc -> gelu -> + residual -> qo f32, 32x64 per wave ----
__global__ __launch_bounds__(256) void k_fc(const unsigned short* __restrict__ xbf,
    const unsigned short* __restrict__ W, const float* __restrict__ qin,
    float* __restrict__ qo){
  int wid = blockIdx.x * 4 + (threadIdx.x >> 6);   // 0..511
  int tm = wid >> 3, tn = wid & 7;
  int lane = threadIdx.x & 63;
  int r = lane & 15, qq = lane >> 4;
  const unsigned short* A  = xbf + (size_t)(tm * 32 + r) * 512 + qq * 8;
  const unsigned short* Bp = W + (size_t)(tn * 64 + r) * 512 + qq * 8;
  f32x4 acc[2][4] = {};
  gemmT<2, 512, 512, 16>(A, Bp, acc);
#pragma unroll
  for (int i = 0; i < 2; i++)
#pragma unroll
    for (int j = 0; j < 4; j++)
#pragma unroll
      for (int e = 0; e < 4; e++){
        int row = tm * 32 + i * 16 + qq * 4 + e;
        int col = tn * 64 + j * 16 + r;
        qo[(size_t)row * 512 + col] = qin[(size_t)row * 512 + col] + gelu_tanh(acc[i][j][e]);
      }
}

extern "C" void kernel_launch(void* const* d_in, const int* in_sizes, int n_in,
                              void* d_out, int out_size, void* d_ws, size_t ws_size,
                              hipStream_t stream){
  const float* q    = (const float*)d_in[0];
  const float* k    = (const float*)d_in[1];
  const float* v    = (const float*)d_in[2];
  const float* vak  = (const float*)d_in[3];
  const float* vav  = (const float*)d_in[4];
  const int*   adjk = (const int*)d_in[5];
  // d_in[6] = adj_v: unused by the reference
  const float* wqs  = (const float*)d_in[7];
  const float* wks  = (const float*)d_in[8];
  const float* wvs  = (const float*)d_in[9];
  const float* wfc  = (const float*)d_in[10];
  const float* wnw  = (const float*)d_in[11];
  const float* wself= (const float*)d_in[12];
  const float* wdd  = (const float*)d_in[13];

  float* qo    = (float*)d_out;               // [4,512,512]
  float* attnF = qo + 1048576;                // [4,8,512,512]

  char* p = (char*)d_ws;
  unsigned short* xin   = (unsigned short*)p; p += 6291456;   // q,k,v bf16
  unsigned short* Wt    = (unsigned short*)p; p += 3145728;   // 6 transposed weights bf16
  unsigned short* qsb   = (unsigned short*)p; p += 2097152;   // [B,H,L,D]
  unsigned short* khb   = (unsigned short*)p; p += 2097152;   // [B,H,L,D]
  unsigned short* vhT   = (unsigned short*)p; p += 2097152;   // [B,H,D,L]
  unsigned short* attnb = (unsigned short*)p; p += 16777216;  // [B,H,L,L] bf16
  float*          qc    = (float*)p;          p += 4194304;   // [2048,512]
  unsigned short* qcb   = (unsigned short*)p; p += 2097152;
  float*          nw    = (float*)p;          p += 8192;
  float*          invd  = (float*)p;          p += 8192;
  float*          selfi = (float*)p;          p += 4194304;
  unsigned short* ddT   = (unsigned short*)p; p += 2097152;   // [B, n, m] bf16
  unsigned short* ddw   = (unsigned short*)p; p += 2097152;   // [B, l, m] bf16
  unsigned short* xbf   = (unsigned short*)p; p += 2097152;

  k_prep<<<3264, 256, 0, stream>>>(q, k, v, xin, wqs, wks, wvs, wself, wdd, wfc, Wt);
  k_proj<<<384, 256, 0, stream>>>(xin, Wt, qsb, khb, vhT);
  k_scores<<<512, 256, 0, stream>>>(qsb, khb, attnF);
  k_relsoft<<<2048, 256, 0, stream>>>(qsb, vak, adjk, attnF, attnb);
  k_outc<<<128, 256, 0, stream>>>(attnb, vhT, qc);
  k_outrel<<<2048, 256, 0, stream>>>(attnb, vav, qc, adjk, wnw, qcb, nw, invd);
  k_post<<<768, 256, 0, stream>>>(qcb, Wt + 786432, Wt + 1048576, selfi, ddT,
                                  adjk, nw, invd, ddw);
  k_agg<<<128, 256, 0, stream>>>(ddw, ddT, selfi, xbf);
  k_fc<<<128, 256, 0, stream>>>(xbf, Wt + 1310720, q, qo);
}